// Round 3
// baseline (313.780 us; speedup 1.0000x reference)
//
#include <hip/hip_runtime.h>
#include <cstdint>
#include <cstddef>

// VQ-VAE quantization forward, MI355X/gfx950 — bf16 split-precision MFMA version.
// dot(x, e_norm) = xh*eh + xh*el + xl*eh  (3x mfma_f32_16x16x32_bf16, fp32 accum)
//
// v4: 256 blocks x 896 threads (14 waves). Block covers 100 rows (7 tiles x 16,
// 12 padded slots). Wave pair (row-tile, code-half): 16 rows x 128 codes/wave,
// acc 32 VGPR -> high occupancy (~3.5 waves/SIMD). Triple-buffered 32KB chunk
// staging with ONE barrier/iter, counted vmcnt (6 stagers / 2 others),
// v2's measured-conflict-free LDS read pattern, setprio around MFMA.

typedef __attribute__((ext_vector_type(8))) short short8;
typedef __attribute__((ext_vector_type(4))) float f32x4;

namespace {
constexpr int kNT = 25600;           // N*T rows
constexpr int kD  = 1024;            // feature dim
constexpr int kM  = 256;             // codebook size
constexpr size_t kQElems = (size_t)kNT * kD;

// ws layout (float units). Codebook images: 32 chunks x [n=256][k=32] bf16,
// 16B sub-blocks swizzled: element idx = c*8192 + n*32 + (g ^ ((n>>1)&3))*8 + (k&7)
constexpr int WS_IMG_H = 0;                    // 262144 ushort = 131072 floats
constexpr int WS_IMG_L = 131072;               // 262144 ushort
constexpr int WS_E2N   = 262144;               // ||e_norm||^2 (256)
constexpr int WS_SCL   = WS_E2N + kM;          // ||e_raw|| + 1e-4 (256)
constexpr int WS_E2R   = WS_SCL + kM;          // ||e_raw||^2 (256)
constexpr int WS_COM   = WS_E2R + kM;          // commitment accumulator
constexpr int WS_HIST  = WS_COM + 4;           // histogram 256 ints
constexpr int WS_ZERO_BYTES = (WS_HIST + kM - WS_COM) * 4;
}

typedef __attribute__((address_space(3))) unsigned int        lds_u32;
typedef const __attribute__((address_space(1))) unsigned int  glb_u32;
typedef const __attribute__((address_space(3))) char          lds_chc;

__device__ __forceinline__ void gl2lds16(const void* g, void* l) {
  __builtin_amdgcn_global_load_lds((glb_u32*)g, (lds_u32*)l, 16, 0, 0);
}

// inline-asm LDS read: compile-time offset immediate; lgkmcnt counted manually
// (rule #18: lgkmcnt asm + sched_barrier(0) before dependent MFMAs).
template <int OFF>
__device__ __forceinline__ short8 ldsr(lds_chc* p) {
  short8 r;
  asm volatile("ds_read_b128 %0, %1 offset:%c2" : "=v"(r) : "v"(p), "i"(OFF));
  return r;
}

// ---------------- kernel 1: normalize codebook -> swizzled bf16 hi/lo images + stats ----
__global__ __launch_bounds__(256) void vq_normalize(const float* __restrict__ emb,
                                                    float* __restrict__ ws) {
  const int m = blockIdx.x;
  const int t = threadIdx.x;
  const float4 v = reinterpret_cast<const float4*>(emb + (size_t)m * kD)[t];
  float s = v.x * v.x + v.y * v.y + v.z * v.z + v.w * v.w;
#pragma unroll
  for (int mask = 32; mask >= 1; mask >>= 1) s += __shfl_xor(s, mask);
  __shared__ float red[4];
  if ((t & 63) == 0) red[t >> 6] = s;
  __syncthreads();
  const float tot = red[0] + red[1] + red[2] + red[3];
  const float sc  = sqrtf(tot) + 1e-4f;
  const float inv = 1.0f / sc;
  const float4 nv = make_float4(v.x * inv, v.y * inv, v.z * inv, v.w * inv);

  float s2 = nv.x * nv.x + nv.y * nv.y + nv.z * nv.z + nv.w * nv.w;
#pragma unroll
  for (int mask = 32; mask >= 1; mask >>= 1) s2 += __shfl_xor(s2, mask);
  __syncthreads();
  if ((t & 63) == 0) red[t >> 6] = s2;
  __syncthreads();
  if (t == 0) {
    ws[WS_E2N + m] = red[0] + red[1] + red[2] + red[3];
    ws[WS_SCL + m] = sc;
    ws[WS_E2R + m] = tot;
  }

  // hi/lo truncation split, packed to the swizzled image
  unsigned short* imgh = (unsigned short*)(ws + WS_IMG_H);
  unsigned short* imgl = (unsigned short*)(ws + WS_IMG_L);
  const int c  = t >> 3;              // k-chunk (k = 4t..4t+3)
  const int g  = (t >> 1) & 3;        // 8-elem group within chunk
  const int sq = g ^ ((m >> 1) & 3);  // bank swizzle
  const int base = c * 8192 + m * 32 + sq * 8 + 4 * (t & 1);
  ushort4 hq, lq;
#pragma unroll
  for (int j = 0; j < 4; ++j) {
    const float fv = (&nv.x)[j];
    const unsigned int b = __float_as_uint(fv);
    const unsigned short hi = (unsigned short)(b >> 16);
    const float lof = fv - __uint_as_float(b & 0xFFFF0000u);
    const unsigned short lo = (unsigned short)(__float_as_uint(lof) >> 16);
    (&hq.x)[j] = hi; (&lq.x)[j] = lo;
  }
  *(ushort4*)(imgh + base) = hq;
  *(ushort4*)(imgl + base) = lq;
}

// ---------------- kernel 2: MFMA distances + argmin + gather + stats ----------------
// 256 blocks x 896 threads (14 waves). Wave w: row-tile rt=w>>1 (16 rows at
// blk*100 + rt*16), code-half ch=w&1 (128 codes). Full K=1024 per wave.
// Per K-chunk of 32: waves 0-7 stage the 32KB hi+lo chunk into buf[(j+1)%3]
// (4KB each, linear dest); all waves read buf[j%3].

// read hi+lo fragments for 4 code tiles (T0..T0+3) from base LB
#define RD8(LB, T0, H0, H1, H2, H3, L0, L1, L2, L3)                            \
  H0 = ldsr<((T0) + 0) * 1024>(LB);                                            \
  H1 = ldsr<((T0) + 1) * 1024>(LB);                                            \
  H2 = ldsr<((T0) + 2) * 1024>(LB);                                            \
  H3 = ldsr<((T0) + 3) * 1024>(LB);                                            \
  L0 = ldsr<16384 + ((T0) + 0) * 1024>(LB);                                    \
  L1 = ldsr<16384 + ((T0) + 1) * 1024>(LB);                                    \
  L2 = ldsr<16384 + ((T0) + 2) * 1024>(LB);                                    \
  L3 = ldsr<16384 + ((T0) + 3) * 1024>(LB);

// 12 MFMAs for tiles T0..T0+3 (3-term split), round-robin -> dep distance 4
#define MM12(T0, H0, H1, H2, H3, L0, L1, L2, L3)                                                 \
  acc[(T0) + 0] = __builtin_amdgcn_mfma_f32_16x16x32_bf16(ah, H0, acc[(T0) + 0], 0, 0, 0);       \
  acc[(T0) + 1] = __builtin_amdgcn_mfma_f32_16x16x32_bf16(ah, H1, acc[(T0) + 1], 0, 0, 0);       \
  acc[(T0) + 2] = __builtin_amdgcn_mfma_f32_16x16x32_bf16(ah, H2, acc[(T0) + 2], 0, 0, 0);       \
  acc[(T0) + 3] = __builtin_amdgcn_mfma_f32_16x16x32_bf16(ah, H3, acc[(T0) + 3], 0, 0, 0);       \
  acc[(T0) + 0] = __builtin_amdgcn_mfma_f32_16x16x32_bf16(ah, L0, acc[(T0) + 0], 0, 0, 0);       \
  acc[(T0) + 1] = __builtin_amdgcn_mfma_f32_16x16x32_bf16(ah, L1, acc[(T0) + 1], 0, 0, 0);       \
  acc[(T0) + 2] = __builtin_amdgcn_mfma_f32_16x16x32_bf16(ah, L2, acc[(T0) + 2], 0, 0, 0);       \
  acc[(T0) + 3] = __builtin_amdgcn_mfma_f32_16x16x32_bf16(ah, L3, acc[(T0) + 3], 0, 0, 0);       \
  acc[(T0) + 0] = __builtin_amdgcn_mfma_f32_16x16x32_bf16(al, H0, acc[(T0) + 0], 0, 0, 0);       \
  acc[(T0) + 1] = __builtin_amdgcn_mfma_f32_16x16x32_bf16(al, H1, acc[(T0) + 1], 0, 0, 0);       \
  acc[(T0) + 2] = __builtin_amdgcn_mfma_f32_16x16x32_bf16(al, H2, acc[(T0) + 2], 0, 0, 0);       \
  acc[(T0) + 3] = __builtin_amdgcn_mfma_f32_16x16x32_bf16(al, L3 /*unused*/, acc[(T0) + 3], 0, 0, 0);

// NOTE: last line above must use H3 (al*hi term). Defined correctly below.
#undef MM12
#define MM12(T0, H0, H1, H2, H3, L0, L1, L2, L3)                                                 \
  acc[(T0) + 0] = __builtin_amdgcn_mfma_f32_16x16x32_bf16(ah, H0, acc[(T0) + 0], 0, 0, 0);       \
  acc[(T0) + 1] = __builtin_amdgcn_mfma_f32_16x16x32_bf16(ah, H1, acc[(T0) + 1], 0, 0, 0);       \
  acc[(T0) + 2] = __builtin_amdgcn_mfma_f32_16x16x32_bf16(ah, H2, acc[(T0) + 2], 0, 0, 0);       \
  acc[(T0) + 3] = __builtin_amdgcn_mfma_f32_16x16x32_bf16(ah, H3, acc[(T0) + 3], 0, 0, 0);       \
  acc[(T0) + 0] = __builtin_amdgcn_mfma_f32_16x16x32_bf16(ah, L0, acc[(T0) + 0], 0, 0, 0);       \
  acc[(T0) + 1] = __builtin_amdgcn_mfma_f32_16x16x32_bf16(ah, L1, acc[(T0) + 1], 0, 0, 0);       \
  acc[(T0) + 2] = __builtin_amdgcn_mfma_f32_16x16x32_bf16(ah, L2, acc[(T0) + 2], 0, 0, 0);       \
  acc[(T0) + 3] = __builtin_amdgcn_mfma_f32_16x16x32_bf16(ah, L3, acc[(T0) + 3], 0, 0, 0);       \
  acc[(T0) + 0] = __builtin_amdgcn_mfma_f32_16x16x32_bf16(al, H0, acc[(T0) + 0], 0, 0, 0);       \
  acc[(T0) + 1] = __builtin_amdgcn_mfma_f32_16x16x32_bf16(al, H1, acc[(T0) + 1], 0, 0, 0);       \
  acc[(T0) + 2] = __builtin_amdgcn_mfma_f32_16x16x32_bf16(al, H2, acc[(T0) + 2], 0, 0, 0);       \
  acc[(T0) + 3] = __builtin_amdgcn_mfma_f32_16x16x32_bf16(al, H3, acc[(T0) + 3], 0, 0, 0);

// split 8 consecutive k floats into hi/lo bf16 frags; accumulate x2
#define CONV8(F0, F1)                                                          \
  {                                                                            \
    union { short8 v; unsigned short u[8]; } H_, L_;                           \
    const float fx_[8] = {F0.x, F0.y, F0.z, F0.w, F1.x, F1.y, F1.z, F1.w};     \
    _Pragma("unroll")                                                          \
    for (int jj_ = 0; jj_ < 8; ++jj_) {                                        \
      const float fv_ = fx_[jj_];                                              \
      const unsigned int b_ = __float_as_uint(fv_);                            \
      H_.u[jj_] = (unsigned short)(b_ >> 16);                                  \
      const float lo_ = fv_ - __uint_as_float(b_ & 0xFFFF0000u);               \
      L_.u[jj_] = (unsigned short)(__float_as_uint(lo_) >> 16);                \
      x2 += fv_ * fv_;                                                         \
    }                                                                          \
    ah = H_.v; al = L_.v;                                                      \
  }

// one K-chunk iteration. RB = read buffer (KC%3), SB = stage buffer ((KC+1)%3).
// Stagers: vmcnt(6) = this iter's 2 x-loads + 4 stage ops in flight; forces
// stage(KC) + x(KC) complete. Non-stagers: vmcnt(2).
#define VQ_ITER4(KC, RB, SB, XC0, XC1, XN0, XN1)                               \
  {                                                                            \
    const int kcn_ = ((KC) < 31) ? (KC) + 1 : 31;                              \
    const float* xp_ = xrow + kcn_ * 32;                                       \
    XN0 = *(const float4*)xp_;                                                 \
    XN1 = *(const float4*)(xp_ + 4);                                           \
    if (stg) {                                                                 \
      const unsigned short* sg_ = simg + ((size_t)kcn_ << 13) + soff;          \
      char* dg_ = &buf[SB][0] + ldst;                                          \
      _Pragma("unroll")                                                        \
      for (int it_ = 0; it_ < 4; ++it_)                                        \
        gl2lds16(sg_ + it_ * 512, dg_ + it_ * 1024);                           \
      asm volatile("s_waitcnt vmcnt(6)" ::: "memory");                         \
    } else {                                                                   \
      asm volatile("s_waitcnt vmcnt(2)" ::: "memory");                         \
    }                                                                          \
    __builtin_amdgcn_s_barrier();                                              \
    asm volatile("" ::: "memory");                                             \
    lds_chc* lb_ = lbase + (RB) * 32768;                                       \
    short8 h0_, h1_, h2_, h3_, l0_, l1_, l2_, l3_;                             \
    RD8(lb_, 0, h0_, h1_, h2_, h3_, l0_, l1_, l2_, l3_)                        \
    short8 ah, al;                                                             \
    CONV8(XC0, XC1)                                                            \
    asm volatile("s_waitcnt lgkmcnt(0)" ::: "memory");                         \
    __builtin_amdgcn_sched_barrier(0);                                         \
    __builtin_amdgcn_s_setprio(1);                                             \
    MM12(0, h0_, h1_, h2_, h3_, l0_, l1_, l2_, l3_)                            \
    __builtin_amdgcn_s_setprio(0);                                             \
    RD8(lb_, 4, h0_, h1_, h2_, h3_, l0_, l1_, l2_, l3_)                        \
    asm volatile("s_waitcnt lgkmcnt(0)" ::: "memory");                         \
    __builtin_amdgcn_sched_barrier(0);                                         \
    __builtin_amdgcn_s_setprio(1);                                             \
    MM12(4, h0_, h1_, h2_, h3_, l0_, l1_, l2_, l3_)                            \
    __builtin_amdgcn_s_setprio(0);                                             \
  }

__global__ __launch_bounds__(896, 1) void vq_main(const float* __restrict__ x,
                                                  const float* __restrict__ emb,
                                                  const float* __restrict__ wsc,
                                                  float* __restrict__ out,
                                                  float* __restrict__ commit_sum,
                                                  int* __restrict__ hist) {
  __shared__ char buf[3][32768];   // per buffer: [hi 16KB][lo 16KB] of one k-chunk
  __shared__ float e2n_s[kM], scl_s[kM], e2r_s[kM];
  __shared__ float bvp[7][2][16];
  __shared__ int   bjp[7][2][16];
  __shared__ int   idx_s[112];

  const int t   = threadIdx.x;
  const int l   = t & 63;
  const int w   = t >> 6;          // 0..13
  const int rt  = w >> 1;          // row tile 0..6
  const int ch  = w & 1;           // code half
  const int nlo = l & 15;          // row within tile
  const int kq  = l >> 4;          // k-quad
  const int blk0 = blockIdx.x * 100;
  const int lrow = rt * 16 + nlo;                  // 0..111 (valid < 100)
  const int growc = (blk0 + lrow < kNT) ? (blk0 + lrow) : (kNT - 1);
  const float* xrow = x + (size_t)growc * kD + kq * 8;

  if (t < kM) {
    e2n_s[t] = wsc[WS_E2N + t];
    scl_s[t] = wsc[WS_SCL + t];
    e2r_s[t] = wsc[WS_E2R + t];
  }

  // staging assignment: waves 0-3 -> hi quarters, 4-7 -> lo quarters
  const bool stg = (w < 8);
  const unsigned short* imgH = (const unsigned short*)(wsc + WS_IMG_H);
  const unsigned short* imgL = (const unsigned short*)(wsc + WS_IMG_L);
  const unsigned short* simg = (w < 4) ? imgH : imgL;
  const int part = w & 3;
  const int soff = part * 2048 + l * 8;                       // elems in half-chunk
  const int ldst = ((w < 4) ? 0 : 16384) + part * 4096;       // bytes in buf[b]

  // v2's measured-conflict-free read pattern, shifted by code-half
  const int sq = kq ^ ((nlo >> 1) & 3);
  lds_chc* lbase = (lds_chc*)&buf[0][0] + ch * 8192 + nlo * 64 + sq * 16;

  f32x4 acc[8];
#pragma unroll
  for (int i = 0; i < 8; ++i) acc[i] = (f32x4)0.0f;
  float x2 = 0.0f;

  __syncthreads();   // stats visible

  // prologue: x(0) + stage chunk 0 -> buf[0]
  float4 xa0 = *(const float4*)xrow;
  float4 xa1 = *(const float4*)(xrow + 4);
  float4 xb0, xb1;
  if (stg) {
    const unsigned short* sg = simg + soff;
    char* dg = &buf[0][0] + ldst;
#pragma unroll
    for (int it = 0; it < 4; ++it) gl2lds16(sg + it * 512, dg + it * 1024);
  }

#pragma unroll 1
  for (int kk = 0; kk < 30; kk += 6) {
    VQ_ITER4(kk,     0, 1, xa0, xa1, xb0, xb1)
    VQ_ITER4(kk + 1, 1, 2, xb0, xb1, xa0, xa1)
    VQ_ITER4(kk + 2, 2, 0, xa0, xa1, xb0, xb1)
    VQ_ITER4(kk + 3, 0, 1, xb0, xb1, xa0, xa1)
    VQ_ITER4(kk + 4, 1, 2, xa0, xa1, xb0, xb1)
    VQ_ITER4(kk + 5, 2, 0, xb0, xb1, xa0, xa1)
  }
  VQ_ITER4(30, 0, 1, xa0, xa1, xb0, xb1)
  VQ_ITER4(31, 1, 2, xb0, xb1, xa0, xa1)

  // ---- ||x_row||^2: reduce across k-quads; all lanes with same nlo hold row total
  x2 += __shfl_xor(x2, 16);
  x2 += __shfl_xor(x2, 32);

  // ---- in-register argmin over this wave's 128 codes.
  // acc[ct][rg] at lane l = dot(row kq*4+rg, code ch*128+ct*16+nlo)
  float bv[4] = {3.0e38f, 3.0e38f, 3.0e38f, 3.0e38f};
  int   bj[4] = {0, 0, 0, 0};
#pragma unroll
  for (int ct = 0; ct < 8; ++ct) {
    const int j = ch * 128 + ct * 16 + nlo;
    const float e = e2n_s[j];
#pragma unroll
    for (int rg = 0; rg < 4; ++rg) {
      const float v = e - 2.0f * acc[ct][rg];
      if (v < bv[rg] || (v == bv[rg] && j < bj[rg])) { bv[rg] = v; bj[rg] = j; }
    }
  }
#pragma unroll
  for (int mk = 1; mk <= 8; mk <<= 1) {   // butterfly across nlo (preserves kq)
#pragma unroll
    for (int rg = 0; rg < 4; ++rg) {
      const float ov = __shfl_xor(bv[rg], mk);
      const int   oj = __shfl_xor(bj[rg], mk);
      if (ov < bv[rg] || (ov == bv[rg] && oj < bj[rg])) { bv[rg] = ov; bj[rg] = oj; }
    }
  }
  if (nlo == 0) {
#pragma unroll
    for (int rg = 0; rg < 4; ++rg) {
      bvp[rt][ch][kq * 4 + rg] = bv[rg];
      bjp[rt][ch][kq * 4 + rg] = bj[rg];
    }
  }
  __syncthreads();

  // ---- combine code-halves, stats (code-half-0 waves)
  if (ch == 0) {
    float clq = 0.0f;
#pragma unroll
    for (int rg = 0; rg < 4; ++rg) {
      const int r = kq * 4 + rg;
      float v0 = bvp[rt][0][r]; int j0 = bjp[rt][0][r];
      const float v1 = bvp[rt][1][r]; const int j1 = bjp[rt][1][r];
      if (v1 < v0 || (v1 == v0 && j1 < j0)) { v0 = v1; j0 = j1; }
      const float xr2 = __shfl(x2, r);     // lane r holds row r's ||x||^2
      const bool valid = (rt * 16 + r) < 100;
      if (nlo == 0) {
        idx_s[rt * 16 + r] = j0;
        if (valid) atomicAdd(&hist[j0], 1);
      }
      if (valid)
        clq += xr2 + e2r_s[j0] - (e2n_s[j0] - v0) * scl_s[j0];
    }
    float cs = (nlo == 0) ? clq : 0.0f;
#pragma unroll
    for (int mk = 1; mk <= 32; mk <<= 1) cs += __shfl_xor(cs, mk);
    if (l == 0) atomicAdd(commit_sum, cs);
  }
  __syncthreads();

  // ---- gather: quantized row = raw embedding[argmin]; wave w -> rows w*8..+8
  const float4* emb4 = (const float4*)emb;
  float4* out4 = (float4*)out;
#pragma unroll
  for (int rr = 0; rr < 8; ++rr) {
    const int lr = w * 8 + rr;
    if (lr < 100) {
      const int j = idx_s[lr];
      const float4* s = emb4 + (size_t)j * (kD / 4);
      float4* d = out4 + (size_t)(blk0 + lr) * (kD / 4);
#pragma unroll
      for (int c = 0; c < 4; ++c) d[c * 64 + l] = s[c * 64 + l];
    }
  }
}

// ---------------- kernel 3: scalars ----------------
__global__ __launch_bounds__(256) void vq_final(const int* __restrict__ hist,
                                                const float* __restrict__ commit_sum,
                                                float* __restrict__ out) {
  const int t = threadIdx.x;
  const float p = (float)hist[t] * (1.0f / (float)kNT);
  float s = p * logf(p + 1e-10f);
#pragma unroll
  for (int mask = 32; mask >= 1; mask >>= 1) s += __shfl_xor(s, mask);
  __shared__ float red[4];
  if ((t & 63) == 0) red[t >> 6] = s;
  __syncthreads();
  if (t == 0) {
    const float ent = red[0] + red[1] + red[2] + red[3];
    out[kQElems]     = commit_sum[0] * (1.0f / (float)kQElems);
    out[kQElems + 1] = expf(-ent);
  }
}

extern "C" void kernel_launch(void* const* d_in, const int* in_sizes, int n_in,
                              void* d_out, int out_size, void* d_ws, size_t ws_size,
                              hipStream_t stream) {
  (void)in_sizes; (void)n_in; (void)out_size; (void)ws_size;
  const float* x   = (const float*)d_in[0];
  const float* emb = (const float*)d_in[1];
  float* out = (float*)d_out;
  float* ws  = (float*)d_ws;

  hipMemsetAsync((char*)d_ws + (size_t)WS_COM * 4, 0, WS_ZERO_BYTES, stream);
  hipLaunchKernelGGL(vq_normalize, dim3(kM), dim3(256), 0, stream, emb, ws);
  hipLaunchKernelGGL(vq_main, dim3(256), dim3(896), 0, stream,
                     x, emb, ws, out, ws + WS_COM, (int*)(ws + WS_HIST));
  hipLaunchKernelGGL(vq_final, dim3(1), dim3(256), 0, stream,
                     (const int*)(ws + WS_HIST), ws + WS_COM, out);
}

// Round 5
// 228.321 us; speedup vs baseline: 1.3743x; 1.3743x over previous
//
#include <hip/hip_runtime.h>
#include <cstdint>
#include <cstddef>

// VQ-VAE quantization forward, MI355X/gfx950 — bf16 split-precision MFMA version.
// dot(x, e_norm) = xh*eh + xh*el + xl*eh  (3x mfma_f32_16x16x32_bf16, fp32 accum)
//
// v6 = v5 + post-loop vmcnt(0) drain with register keep-alive (v5 crashed:
// asm-issued loads still in flight at loop exit clobbered reallocated VGPRs).
//
// v5 design: 400 blocks x 256 threads (4 waves), 2 blocks/CU.
//  - Wave w: codes [w*64,+64), ALL 64 block rows (4 A-tiles), full K.
//    B-fragment reads amortize over 64 rows -> LDS B traffic 4x lower than v2.
//  - x converted to bf16 hi/lo ONCE per block (wave w converts rows [w*16,+16))
//    and shared via a double-buffered LDS X-frag buffer -> 4x less conversion VALU.
//  - B slices are per-wave (no sharing) -> staging is barrier-free (own counted
//    vmcnt); ONE s_barrier per K-chunk (X dbuf swap).
//  - All loop memory ops are inline-asm/builtin with counted vmcnt/lgkmcnt
//    (+ sched_barrier(0) per rule #18); no compiler-inserted drains.

typedef __attribute__((ext_vector_type(8))) short short8;
typedef __attribute__((ext_vector_type(4))) float f32x4;

namespace {
constexpr int kNT = 25600;           // N*T rows
constexpr int kD  = 1024;            // feature dim
constexpr int kM  = 256;             // codebook size
constexpr size_t kQElems = (size_t)kNT * kD;

// ws layout (float units). Codebook images: 32 chunks x [n=256][k=32] bf16,
// 16B sub-blocks swizzled: element idx = c*8192 + n*32 + (g ^ ((n>>1)&3))*8 + (k&7)
constexpr int WS_IMG_H = 0;                    // 262144 ushort = 131072 floats
constexpr int WS_IMG_L = 131072;               // 262144 ushort
constexpr int WS_E2N   = 262144;               // ||e_norm||^2 (256)
constexpr int WS_SCL   = WS_E2N + kM;          // ||e_raw|| + 1e-4 (256)
constexpr int WS_E2R   = WS_SCL + kM;          // ||e_raw||^2 (256)
constexpr int WS_COM   = WS_E2R + kM;          // commitment accumulator
constexpr int WS_HIST  = WS_COM + 4;           // histogram 256 ints
constexpr int WS_ZERO_BYTES = (WS_HIST + kM - WS_COM) * 4;
}

typedef __attribute__((address_space(3))) unsigned int        lds_u32;
typedef const __attribute__((address_space(1))) unsigned int  glb_u32;
typedef const __attribute__((address_space(3))) char          lds_chc;

__device__ __forceinline__ void gl2lds16(const void* g, void* l) {
  __builtin_amdgcn_global_load_lds((glb_u32*)g, (lds_u32*)l, 16, 0, 0);
}

// inline-asm LDS read/write: compile-time offset immediate; lgkmcnt counted
// manually (rule #18: counted wait + sched_barrier(0) before dependent use).
template <int OFF>
__device__ __forceinline__ short8 ldsr(lds_chc* p) {
  short8 r;
  asm volatile("ds_read_b128 %0, %1 offset:%c2" : "=v"(r) : "v"(p), "i"(OFF));
  return r;
}
template <int OFF>
__device__ __forceinline__ void ldsw(lds_chc* p, short8 v) {
  asm volatile("ds_write_b128 %0, %1 offset:%c2" :: "v"(p), "v"(v), "i"(OFF) : "memory");
}
// asm global load: keeps x-loads out of the compiler's vmcnt bookkeeping so our
// counted waits stay exact (mixed C/asm vmem counting breaks otherwise).
__device__ __forceinline__ f32x4 gld4(const float* p) {
  f32x4 r;
  asm volatile("global_load_dwordx4 %0, %1, off" : "=v"(r) : "v"(p));
  return r;
}

// ---------------- kernel 1: normalize codebook -> swizzled bf16 hi/lo images + stats ----
__global__ __launch_bounds__(256) void vq_normalize(const float* __restrict__ emb,
                                                    float* __restrict__ ws) {
  const int m = blockIdx.x;
  const int t = threadIdx.x;
  const float4 v = reinterpret_cast<const float4*>(emb + (size_t)m * kD)[t];
  float s = v.x * v.x + v.y * v.y + v.z * v.z + v.w * v.w;
#pragma unroll
  for (int mask = 32; mask >= 1; mask >>= 1) s += __shfl_xor(s, mask);
  __shared__ float red[4];
  if ((t & 63) == 0) red[t >> 6] = s;
  __syncthreads();
  const float tot = red[0] + red[1] + red[2] + red[3];
  const float sc  = sqrtf(tot) + 1e-4f;
  const float inv = 1.0f / sc;
  const float4 nv = make_float4(v.x * inv, v.y * inv, v.z * inv, v.w * inv);

  float s2 = nv.x * nv.x + nv.y * nv.y + nv.z * nv.z + nv.w * nv.w;
#pragma unroll
  for (int mask = 32; mask >= 1; mask >>= 1) s2 += __shfl_xor(s2, mask);
  __syncthreads();
  if ((t & 63) == 0) red[t >> 6] = s2;
  __syncthreads();
  if (t == 0) {
    ws[WS_E2N + m] = red[0] + red[1] + red[2] + red[3];
    ws[WS_SCL + m] = sc;
    ws[WS_E2R + m] = tot;
  }

  // hi/lo truncation split, packed to the swizzled image
  unsigned short* imgh = (unsigned short*)(ws + WS_IMG_H);
  unsigned short* imgl = (unsigned short*)(ws + WS_IMG_L);
  const int c  = t >> 3;              // k-chunk (k = 4t..4t+3)
  const int g  = (t >> 1) & 3;        // 8-elem group within chunk
  const int sq = g ^ ((m >> 1) & 3);  // bank swizzle
  const int base = c * 8192 + m * 32 + sq * 8 + 4 * (t & 1);
  ushort4 hq, lq;
#pragma unroll
  for (int j = 0; j < 4; ++j) {
    const float fv = (&nv.x)[j];
    const unsigned int b = __float_as_uint(fv);
    const unsigned short hi = (unsigned short)(b >> 16);
    const float lof = fv - __uint_as_float(b & 0xFFFF0000u);
    const unsigned short lo = (unsigned short)(__float_as_uint(lof) >> 16);
    (&hq.x)[j] = hi; (&lq.x)[j] = lo;
  }
  *(ushort4*)(imgh + base) = hq;
  *(ushort4*)(imgl + base) = lq;
}

// ---------------- kernel 2: MFMA distances + argmin + gather + stats ----------------
// LDS map (pool): [0,32768) Bbuf: wave w slice at w*8192 = [hi 4K][lo 4K]
//                 [32768,49152) Xbuf[2]: XB*8192 = [hi 4K][lo 4K], [64 rows][32 k]

// stage wave's own 8KB B slice for chunk KCN (uniform LDS dest, per-lane global src)
#define DMASTAGE(KCN)                                                          \
  {                                                                            \
    const unsigned short* gh_ = imgH + ((size_t)(KCN) << 13) + (w << 11) + (l << 3); \
    const unsigned short* gl_ = imgL + ((size_t)(KCN) << 13) + (w << 11) + (l << 3); \
    gl2lds16(gh_,        BslU);                                                \
    gl2lds16(gh_ +  512, BslU + 1024);                                         \
    gl2lds16(gh_ + 1024, BslU + 2048);                                         \
    gl2lds16(gh_ + 1536, BslU + 3072);                                         \
    gl2lds16(gl_,        BslU + 4096);                                         \
    gl2lds16(gl_ +  512, BslU + 5120);                                         \
    gl2lds16(gl_ + 1024, BslU + 6144);                                         \
    gl2lds16(gl_ + 1536, BslU + 7168);                                         \
  }

// split 8 consecutive k floats (f32x4 pair) into hi/lo bf16 frags; accumulate x2
#define CONV8(F0, F1, AH, AL)                                                  \
  {                                                                            \
    union { short8 v; unsigned short u[8]; } H_, L_;                           \
    _Pragma("unroll")                                                          \
    for (int jj_ = 0; jj_ < 8; ++jj_) {                                        \
      const float fv_ = (jj_ < 4) ? (F0)[jj_] : (F1)[jj_ - 4];                 \
      const unsigned int b_ = __float_as_uint(fv_);                            \
      H_.u[jj_] = (unsigned short)(b_ >> 16);                                  \
      const float lo_ = fv_ - __uint_as_float(b_ & 0xFFFF0000u);               \
      L_.u[jj_] = (unsigned short)(__float_as_uint(lo_) >> 16);                \
      x2 += fv_ * fv_;                                                         \
    }                                                                          \
    AH = H_.v; AL = L_.v;                                                      \
  }

#define MMQ(AR, B0, B1, B2, B3, RT)                                                        \
  acc[RT][0] = __builtin_amdgcn_mfma_f32_16x16x32_bf16(AR, B0, acc[RT][0], 0, 0, 0);       \
  acc[RT][1] = __builtin_amdgcn_mfma_f32_16x16x32_bf16(AR, B1, acc[RT][1], 0, 0, 0);       \
  acc[RT][2] = __builtin_amdgcn_mfma_f32_16x16x32_bf16(AR, B2, acc[RT][2], 0, 0, 0);       \
  acc[RT][3] = __builtin_amdgcn_mfma_f32_16x16x32_bf16(AR, B3, acc[RT][3], 0, 0, 0);
#define MMPASS(A0, A1, A2, A3, B0, B1, B2, B3)                                 \
  MMQ(A0, B0, B1, B2, B3, 0) MMQ(A1, B0, B1, B2, B3, 1)                        \
  MMQ(A2, B0, B1, B2, B3, 2) MMQ(A3, B0, B1, B2, B3, 3)

// one K-chunk. Invariant entering: outstanding VMEM = DMA(c)[8] + xload(c+1)[2].
// XC = regs holding x(c+1) (converting wave's rows), XN = regs for x(c+2).
#define VQ_ITER5(KC, XB, XC0, XC1, XN0, XN1)                                   \
  {                                                                            \
    asm volatile("s_waitcnt vmcnt(2)" ::: "memory");   /* B(c) staged */       \
    __builtin_amdgcn_sched_barrier(0);                                         \
    short8 a0h, a1h, a2h, a3h, a0l, a1l, a2l, a3l;                             \
    short8 b0h, b1h, b2h, b3h, b0l, b1l, b2l, b3l;                             \
    a0h = ldsr<32768 + (XB) * 8192 + 0 * 1024>(pA);                            \
    a1h = ldsr<32768 + (XB) * 8192 + 1 * 1024>(pA);                            \
    a2h = ldsr<32768 + (XB) * 8192 + 2 * 1024>(pA);                            \
    a3h = ldsr<32768 + (XB) * 8192 + 3 * 1024>(pA);                            \
    a0l = ldsr<32768 + (XB) * 8192 + 4096 + 0 * 1024>(pA);                     \
    a1l = ldsr<32768 + (XB) * 8192 + 4096 + 1 * 1024>(pA);                     \
    a2l = ldsr<32768 + (XB) * 8192 + 4096 + 2 * 1024>(pA);                     \
    a3l = ldsr<32768 + (XB) * 8192 + 4096 + 3 * 1024>(pA);                     \
    b0h = ldsr<0 * 1024>(pB);                                                  \
    b1h = ldsr<1 * 1024>(pB);                                                  \
    b2h = ldsr<2 * 1024>(pB);                                                  \
    b3h = ldsr<3 * 1024>(pB);                                                  \
    b0l = ldsr<4096 + 0 * 1024>(pB);                                           \
    b1l = ldsr<4096 + 1 * 1024>(pB);                                           \
    b2l = ldsr<4096 + 2 * 1024>(pB);                                           \
    b3l = ldsr<4096 + 3 * 1024>(pB);                                           \
    asm volatile("s_waitcnt lgkmcnt(0)" ::: "memory"); /* frags in regs */     \
    __builtin_amdgcn_sched_barrier(0);                                         \
    {  /* B reads retired -> safe to overwrite own slice */                    \
      const int kcn_ = ((KC) + 1 < 32) ? (KC) + 1 : 31;                        \
      DMASTAGE(kcn_)                                                           \
    }                                                                          \
    {                                                                          \
      const int kc2_ = ((KC) + 2 < 32) ? (KC) + 2 : 31;                        \
      XN0 = gld4(xrow + kc2_ * 32);                                            \
      XN1 = gld4(xrow + kc2_ * 32 + 4);                                        \
    }                                                                          \
    __builtin_amdgcn_s_setprio(1);                                             \
    MMPASS(a0h, a1h, a2h, a3h, b0h, b1h, b2h, b3h)   /* xh*eh */               \
    MMPASS(a0h, a1h, a2h, a3h, b0l, b1l, b2l, b3l)   /* xh*el */               \
    __builtin_amdgcn_s_setprio(0);                                             \
    asm volatile("s_waitcnt vmcnt(10)" ::: "memory");  /* x(c+1) landed */     \
    __builtin_amdgcn_sched_barrier(0);                                         \
    if ((KC) < 31) {                                                           \
      short8 cah, cal;                                                         \
      CONV8(XC0, XC1, cah, cal)                                                \
      ldsw<32768 + ((XB) ^ 1) * 8192 + 0>(pW, cah);                            \
      ldsw<32768 + ((XB) ^ 1) * 8192 + 4096>(pW, cal);                         \
    }                                                                          \
    __builtin_amdgcn_s_setprio(1);                                             \
    MMPASS(a0l, a1l, a2l, a3l, b0h, b1h, b2h, b3h)   /* xl*eh */               \
    __builtin_amdgcn_s_setprio(0);                                             \
    asm volatile("s_waitcnt lgkmcnt(0)" ::: "memory"); /* X writes done */     \
    __builtin_amdgcn_s_barrier();                                              \
  }

__global__ __launch_bounds__(256, 2) void vq_main(const float* __restrict__ x,
                                                  const float* __restrict__ emb,
                                                  const float* __restrict__ wsc,
                                                  float* __restrict__ out,
                                                  float* __restrict__ commit_sum,
                                                  int* __restrict__ hist) {
  __shared__ char pool[49152];
  __shared__ float x2s[64];
  __shared__ float bvp[4][64];
  __shared__ int   bjp[4][64];
  __shared__ int   idx_s[64];

  const int t   = threadIdx.x;
  const int l   = t & 63;
  const int w   = t >> 6;          // 0..3
  const int nlo = l & 15;
  const int kq  = l >> 4;          // 0..3
  const int blk0 = blockIdx.x * 64;

  const unsigned short* imgH = (const unsigned short*)(wsc + WS_IMG_H);
  const unsigned short* imgL = (const unsigned short*)(wsc + WS_IMG_L);
  char* BslU = pool + w * 8192;                   // uniform DMA dest (own slice)

  // x pointer: converting wave w owns rows [w*16,+16): lane (nlo,kq) -> row w*16+nlo,
  // k = chunk*32 + kq*8
  const float* xrow = x + (size_t)(blk0 + w * 16 + nlo) * kD + kq * 8;

  // LDS lane bases — v2's measured-conflict-free [64][32] tile pattern
  const int sqz = kq ^ ((nlo >> 1) & 3);
  lds_chc* base = (lds_chc*)pool;
  lds_chc* pA = base + nlo * 64 + sqz * 16;             // + region offsets (imm)
  lds_chc* pB = base + w * 8192 + nlo * 64 + sqz * 16;  // own B slice
  lds_chc* pW = pA + w * 1024;                          // X write: row w*16+nlo

  f32x4 acc[4][4];
#pragma unroll
  for (int i = 0; i < 4; ++i)
#pragma unroll
    for (int j = 0; j < 4; ++j) acc[i][j] = (f32x4)0.0f;
  float x2 = 0.0f;

  // ---- prologue: x(0), DMA B(0), x(1); convert x(0) -> Xbuf[0]
  f32x4 xa0 = gld4(xrow);
  f32x4 xa1 = gld4(xrow + 4);          // [2 outstanding]
  DMASTAGE(0)                          // [10]
  f32x4 xb0 = gld4(xrow + 32);
  f32x4 xb1 = gld4(xrow + 36);         // [12]
  asm volatile("s_waitcnt vmcnt(10)" ::: "memory");  // x(0) landed
  __builtin_amdgcn_sched_barrier(0);
  {
    short8 cah, cal;
    CONV8(xa0, xa1, cah, cal)
    ldsw<32768 + 0>(pW, cah);
    ldsw<32768 + 4096>(pW, cal);
  }
  asm volatile("s_waitcnt lgkmcnt(0)" ::: "memory");
  __builtin_amdgcn_s_barrier();
  // invariant entering loop: outstanding = DMA(0)[8] + xload(1)[2]

#pragma unroll 1
  for (int kk = 0; kk < 32; kk += 2) {
    VQ_ITER5(kk,     0, xb0, xb1, xa0, xa1)
    VQ_ITER5(kk + 1, 1, xa0, xa1, xb0, xb1)
  }

  // ---- drain all asm-issued VMEM (DMAs + trailing x-loads) BEFORE their
  // destination registers can be reallocated (v5 crash) and before epilogue.
  // Register inputs extend xa*/xb* liveness to this wait.
  asm volatile("s_waitcnt vmcnt(0)"
               :: "v"(xa0), "v"(xa1), "v"(xb0), "v"(xb1) : "memory");

  // ---- ||x_row||^2 for rows w*16+nlo (reduce k-quads)
  x2 += __shfl_xor(x2, 16);
  x2 += __shfl_xor(x2, 32);
  if (l < 16) x2s[w * 16 + l] = x2;

  // ---- per-wave argmin over its 64 codes.
  // acc[rt][ct][rg] at lane (nlo,kq) = dot(row rt*16+kq*4+rg, code w*64+ct*16+nlo)
  float eN[4];
#pragma unroll
  for (int ct = 0; ct < 4; ++ct) eN[ct] = wsc[WS_E2N + w * 64 + ct * 16 + nlo];

  float bv[4][4]; int bj[4][4];        // [rt][rg]
#pragma unroll
  for (int rt = 0; rt < 4; ++rt)
#pragma unroll
    for (int rg = 0; rg < 4; ++rg) { bv[rt][rg] = 3.0e38f; bj[rt][rg] = 0; }
#pragma unroll
  for (int ct = 0; ct < 4; ++ct) {
    const int j = w * 64 + ct * 16 + nlo;
#pragma unroll
    for (int rt = 0; rt < 4; ++rt)
#pragma unroll
      for (int rg = 0; rg < 4; ++rg) {
        const float v = eN[ct] - 2.0f * acc[rt][ct][rg];
        if (v < bv[rt][rg] || (v == bv[rt][rg] && j < bj[rt][rg])) {
          bv[rt][rg] = v; bj[rt][rg] = j;
        }
      }
  }
#pragma unroll
  for (int mk = 1; mk <= 8; mk <<= 1) {   // butterfly across nlo (16-group)
#pragma unroll
    for (int rt = 0; rt < 4; ++rt)
#pragma unroll
      for (int rg = 0; rg < 4; ++rg) {
        const float ov = __shfl_xor(bv[rt][rg], mk);
        const int   oj = __shfl_xor(bj[rt][rg], mk);
        if (ov < bv[rt][rg] || (ov == bv[rt][rg] && oj < bj[rt][rg])) {
          bv[rt][rg] = ov; bj[rt][rg] = oj;
        }
      }
  }
  if (nlo == 0) {
#pragma unroll
    for (int rt = 0; rt < 4; ++rt)
#pragma unroll
      for (int rg = 0; rg < 4; ++rg) {
        const int row = rt * 16 + kq * 4 + rg;
        bvp[w][row] = bv[rt][rg];
        bjp[w][row] = bj[rt][rg];
      }
  }
  __syncthreads();

  // ---- combine across waves + stats (threads 0..63 = wave 0)
  if (t < 64) {
    const int row = t;
    float v = bvp[0][row]; int j = bjp[0][row];
#pragma unroll
    for (int wv = 1; wv < 4; ++wv) {
      const float v2 = bvp[wv][row]; const int j2 = bjp[wv][row];
      if (v2 < v || (v2 == v && j2 < j)) { v = v2; j = j2; }
    }
    idx_s[row] = j;
    atomicAdd(&hist[j], 1);
    // ||x - e_raw||^2 = ||x||^2 + ||e_raw||^2 - (e2n - v)*scl   [(e2n-v) = 2*dot]
    float cl = x2s[row] + wsc[WS_E2R + j] - (wsc[WS_E2N + j] - v) * wsc[WS_SCL + j];
#pragma unroll
    for (int mk = 1; mk <= 32; mk <<= 1) cl += __shfl_xor(cl, mk);
    if (t == 0) atomicAdd(commit_sum, cl);
  }
  __syncthreads();

  // ---- gather: quantized row = raw embedding[argmin]; wave w -> rows w*16..+16
  const float4* emb4 = (const float4*)emb;
  float4* out4 = (float4*)out;
#pragma unroll 2
  for (int rr = 0; rr < 16; ++rr) {
    const int j = idx_s[w * 16 + rr];
    const float4* s = emb4 + (size_t)j * (kD / 4);
    float4* d = out4 + (size_t)(blk0 + w * 16 + rr) * (kD / 4);
#pragma unroll
    for (int c = 0; c < 4; ++c) d[c * 64 + l] = s[c * 64 + l];
  }
}

// ---------------- kernel 3: scalars ----------------
__global__ __launch_bounds__(256) void vq_final(const int* __restrict__ hist,
                                                const float* __restrict__ commit_sum,
                                                float* __restrict__ out) {
  const int t = threadIdx.x;
  const float p = (float)hist[t] * (1.0f / (float)kNT);
  float s = p * logf(p + 1e-10f);
#pragma unroll
  for (int mask = 32; mask >= 1; mask >>= 1) s += __shfl_xor(s, mask);
  __shared__ float red[4];
  if ((t & 63) == 0) red[t >> 6] = s;
  __syncthreads();
  if (t == 0) {
    const float ent = red[0] + red[1] + red[2] + red[3];
    out[kQElems]     = commit_sum[0] * (1.0f / (float)kQElems);
    out[kQElems + 1] = expf(-ent);
  }
}

extern "C" void kernel_launch(void* const* d_in, const int* in_sizes, int n_in,
                              void* d_out, int out_size, void* d_ws, size_t ws_size,
                              hipStream_t stream) {
  (void)in_sizes; (void)n_in; (void)out_size; (void)ws_size;
  const float* x   = (const float*)d_in[0];
  const float* emb = (const float*)d_in[1];
  float* out = (float*)d_out;
  float* ws  = (float*)d_ws;

  hipMemsetAsync((char*)d_ws + (size_t)WS_COM * 4, 0, WS_ZERO_BYTES, stream);
  hipLaunchKernelGGL(vq_normalize, dim3(kM), dim3(256), 0, stream, emb, ws);
  hipLaunchKernelGGL(vq_main, dim3(kNT / 64), dim3(256), 0, stream,
                     x, emb, ws, out, ws + WS_COM, (int*)(ws + WS_HIST));
  hipLaunchKernelGGL(vq_final, dim3(1), dim3(256), 0, stream,
                     (const int*)(ws + WS_HIST), ws + WS_COM, out);
}